// Round 3
// baseline (148.284 us; speedup 1.0000x reference)
//
#include <hip/hip_runtime.h>

#define IMG_W 512
#define IMG_H 512
#define BATCH 64
#define SLAB_ROWS 16
#define SLABS (IMG_H / SLAB_ROWS)   // 32 slabs/image
#define NBLOCKS (BATCH * SLABS)     // 2048 blocks x 256 threads
#define NPIX (BATCH * IMG_W * IMG_H)
#define LDS_ROWS 18                 // 16 output rows + 2 halo

typedef float f32x4 __attribute__((ext_vector_type(4)));

__device__ __forceinline__ float fast_sqrtf(float x) {
    return __builtin_amdgcn_sqrtf(x);
}

// R11: break the phase-lock. R10 (LDS both phases, 2x full-drain barriers) and
// R9 (24 reg loads, 2 serial waits) both sit at ~44-45us with VALUBusy ~26%,
// HBM 18% -> bound by serialized {burst-load, drain, compute} phases, all
// co-resident blocks in lockstep. Fix (T14/T3): stage p via global_load_lds,
// THEN issue t's 12 asm reg-loads, wait vmcnt(12) (p only; t's 12KB stays in
// flight), raw s_barrier (NOT __syncthreads -> would force vmcnt(0)),
// compute p from LDS (~2000cyc, covers t's ~900cyc latency), vmcnt(0),
// compute t from regs. One counted drain instead of two full drains.

typedef const __attribute__((address_space(1))) void gas_void;
typedef __attribute__((address_space(3))) void las_void;

__device__ __forceinline__ void gload_lds16(const float* g, float* l) {
    __builtin_amdgcn_global_load_lds((gas_void*)g, (las_void*)l, 16, 0, 0);
}

#define GLOAD(dst, ptr)                                                        \
    asm volatile("global_load_dwordx4 %0, %1, off" : "=v"(dst) : "v"(ptr))

// Load input row ty-1+I of IMG into regs (y clamped; edges zeroed later).
#define LOADR(I, A, B, IMG)                                                    \
    {                                                                          \
        int yy = ty - 1 + (I);                                                 \
        int yc = yy < 0 ? 0 : (yy > IMG_H - 1 ? IMG_H - 1 : yy);               \
        const float* r_ = (IMG) + ((size_t)yc << 9) + x0;                      \
        GLOAD(A, r_);                                                          \
        GLOAD(B, r_ + 4);                                                      \
    }

// 10-wide window from two f32x4 + shfl halo (image x-edges -> 0).
#define MKWIN(W, A, B)                                                         \
    float W[10];                                                               \
    {                                                                          \
        float l_ = __shfl_up((B)[3], 1, 64);                                   \
        float r_ = __shfl_down((A)[0], 1, 64);                                 \
        W[0] = (lane == 0) ? 0.f : l_;                                         \
        W[1] = (A)[0]; W[2] = (A)[1]; W[3] = (A)[2]; W[4] = (A)[3];            \
        W[5] = (B)[0]; W[6] = (B)[1]; W[7] = (B)[2]; W[8] = (B)[3];            \
        W[9] = (lane == 63) ? 0.f : r_;                                        \
    }

// horizontal 1-2-1 sums of one row (8 wide)
#define MKHS(HS, W)                                                            \
    float HS[8];                                                               \
    _Pragma("unroll")                                                          \
    for (int j = 0; j < 8; ++j)                                                \
        HS[j] = fmaf(2.f, W[j + 1], W[j]) + W[j + 2];

// output row O of image p: store magnitudes
#define DO_OUT_P(O, WA, WB, WC, HSA, HSC)                                      \
    {                                                                          \
        float c_[10];                                                          \
        _Pragma("unroll")                                                      \
        for (int k = 0; k < 10; ++k)                                           \
            c_[k] = fmaf(2.f, WB[k], WA[k]) + WC[k];                           \
        _Pragma("unroll")                                                      \
        for (int j = 0; j < 8; ++j) {                                          \
            float gh = HSC[j] - HSA[j];                                        \
            float gv = c_[j + 2] - c_[j];                                      \
            magp[O][j] = fast_sqrtf(fmaf(gv, gv, fmaf(gh, gh, 1e-18f)));       \
        }                                                                      \
    }

// output row O of image t: fuse |magt - magp| accumulation (no magt array)
#define DO_OUT_T(O, WA, WB, WC, HSA, HSC)                                      \
    {                                                                          \
        float c_[10];                                                          \
        _Pragma("unroll")                                                      \
        for (int k = 0; k < 10; ++k)                                           \
            c_[k] = fmaf(2.f, WB[k], WA[k]) + WC[k];                           \
        _Pragma("unroll")                                                      \
        for (int j = 0; j < 8; ++j) {                                          \
            float gh = HSC[j] - HSA[j];                                        \
            float gv = c_[j + 2] - c_[j];                                      \
            float mt = fast_sqrtf(fmaf(gv, gv, fmaf(gh, gh, 1e-18f)));         \
            lsum += fabsf(mt - magp[O][j]); /* == sqrt(d^2+eps)*(d^2!=0) */    \
        }                                                                      \
    }

#define SOBEL_P(A0, B0, A1, B1, A2, B2, A3, B3, A4, B4, A5, B5)                \
    {                                                                          \
        MKWIN(w0_, A0, B0) MKWIN(w1_, A1, B1) MKWIN(w2_, A2, B2)               \
        MKWIN(w3_, A3, B3) MKWIN(w4_, A4, B4) MKWIN(w5_, A5, B5)               \
        MKHS(h0_, w0_) MKHS(h1_, w1_) MKHS(h2_, w2_)                           \
        MKHS(h3_, w3_) MKHS(h4_, w4_) MKHS(h5_, w5_)                           \
        DO_OUT_P(0, w0_, w1_, w2_, h0_, h2_)                                   \
        DO_OUT_P(1, w1_, w2_, w3_, h1_, h3_)                                   \
        DO_OUT_P(2, w2_, w3_, w4_, h2_, h4_)                                   \
        DO_OUT_P(3, w3_, w4_, w5_, h3_, h5_)                                   \
    }

#define SOBEL_T(A0, B0, A1, B1, A2, B2, A3, B3, A4, B4, A5, B5)                \
    {                                                                          \
        MKWIN(w0_, A0, B0) MKWIN(w1_, A1, B1) MKWIN(w2_, A2, B2)               \
        MKWIN(w3_, A3, B3) MKWIN(w4_, A4, B4) MKWIN(w5_, A5, B5)               \
        MKHS(h0_, w0_) MKHS(h1_, w1_) MKHS(h2_, w2_)                           \
        MKHS(h3_, w3_) MKHS(h4_, w4_) MKHS(h5_, w5_)                           \
        DO_OUT_T(0, w0_, w1_, w2_, h0_, h2_)                                   \
        DO_OUT_T(1, w1_, w2_, w3_, h1_, h3_)                                   \
        DO_OUT_T(2, w2_, w3_, w4_, h2_, h4_)                                   \
        DO_OUT_T(3, w3_, w4_, w5_, h3_, h5_)                                   \
    }

// Stage the 18 (y-clamped) rows of img into smem. 36 chunks of 1 KB; wave w
// issues chunks w*9..w*9+8. LDS dest linear (global_load_lds: uniform base +
// lane*16); validated in R10.
#define STAGE_IMG(IMG)                                                         \
    {                                                                          \
        _Pragma("unroll")                                                      \
        for (int k = 0; k < 9; ++k) {                                          \
            const int c = w * 9 + k;            /* chunk 0..35, wave-uniform */\
            int ys = row0 + (c >> 1);                                          \
            ys = ys < 0 ? 0 : (ys > IMG_H - 1 ? IMG_H - 1 : ys);               \
            gload_lds16((IMG) + ((size_t)ys << 9) + ((c & 1) << 8) + (lane << 2), \
                        smem + (c << 8) + (lane << 2));                        \
        }                                                                      \
    }

// Load the wave's 6 p-rows (block-local rows 4w..4w+5) as A/B f32x4 pairs.
#define LDS_ROWS_TO_REGS()                                                     \
    A0p = s4[rbase + 0 * 128 + cidx]; B0p = s4[rbase + 0 * 128 + cidx + 1];    \
    A1p = s4[rbase + 1 * 128 + cidx]; B1p = s4[rbase + 1 * 128 + cidx + 1];    \
    A2p = s4[rbase + 2 * 128 + cidx]; B2p = s4[rbase + 2 * 128 + cidx + 1];    \
    A3p = s4[rbase + 3 * 128 + cidx]; B3p = s4[rbase + 3 * 128 + cidx + 1];    \
    A4p = s4[rbase + 4 * 128 + cidx]; B4p = s4[rbase + 4 * 128 + cidx + 1];    \
    A5p = s4[rbase + 5 * 128 + cidx]; B5p = s4[rbase + 5 * 128 + cidx + 1];

__global__ __launch_bounds__(256) void sobel_loss_kernel(
    const float* __restrict__ yp, const float* __restrict__ yt,
    float* __restrict__ bsums)
{
    __shared__ float smem[LDS_ROWS * IMG_W];   // 36 KB, p only
    __shared__ float wred[4];

    const int tid  = threadIdx.x;
    const int lane = tid & 63;
    const int w    = tid >> 6;                  // wave id 0..3

    // XCD-contiguous swizzle (bijective: 2048 % 8 == 0).
    const int bid0 = blockIdx.x;
    const int bid  = (bid0 & 7) * (NBLOCKS / 8) + (bid0 >> 3);

    const int b    = bid >> 5;                  // image (32 slabs/image)
    const int slab = bid & (SLABS - 1);
    const int row0 = slab * SLAB_ROWS - 1;      // top halo source row (may be -1)
    const int ty   = slab * SLAB_ROWS + (w << 2);  // wave's first output row
    const int x0   = lane << 3;                 // cols x0..x0+7

    const float* imgp = yp + ((size_t)b << 18);
    const float* imgt = yt + ((size_t)b << 18);

    const f32x4* s4 = (const f32x4*)smem;
    const int rbase = (w << 2) * (IMG_W / 4);   // block-local row 4w, in f32x4
    const int cidx  = lane << 1;                // lane*8 floats = lane*2 f32x4

    const f32x4 z4 = {0.f, 0.f, 0.f, 0.f};
    f32x4 A0p, B0p, A1p, B1p, A2p, B2p, A3p, B3p, A4p, B4p, A5p, B5p;
    f32x4 A0t, B0t, A1t, B1t, A2t, B2t, A3t, B3t, A4t, B4t, A5t, B5t;

    float magp[4][8];
    float lsum = 0.f;

    // ---- issue p-stage (9 global_load_lds/wave) then t reg-loads (12) ----
    STAGE_IMG(imgp)
    LOADR(0, A0t, B0t, imgt) LOADR(1, A1t, B1t, imgt) LOADR(2, A2t, B2t, imgt)
    LOADR(3, A3t, B3t, imgt) LOADR(4, A4t, B4t, imgt) LOADR(5, A5t, B5t, imgt)

    // ---- wait p staged only (t's 12KB stays in flight); raw barrier ----
    asm volatile("s_waitcnt vmcnt(12)" ::: "memory");
    __builtin_amdgcn_s_barrier();
    __builtin_amdgcn_sched_barrier(0);          // no LDS-read hoisting

    // ---- compute p from LDS (covers t's in-flight latency) ----
    LDS_ROWS_TO_REGS()
    if (ty == 0)         { A0p = z4; B0p = z4; }   // 'SAME' zero pad (y)
    if (ty + 4 == IMG_H) { A5p = z4; B5p = z4; }
    SOBEL_P(A0p, B0p, A1p, B1p, A2p, B2p, A3p, B3p, A4p, B4p, A5p, B5p)

    // ---- wait t, compute fused difference (private regs: no barrier) ----
    asm volatile("s_waitcnt vmcnt(0)"
                 : "+v"(A0t), "+v"(B0t), "+v"(A1t), "+v"(B1t),
                   "+v"(A2t), "+v"(B2t), "+v"(A3t), "+v"(B3t),
                   "+v"(A4t), "+v"(B4t), "+v"(A5t), "+v"(B5t));
    if (ty == 0)         { A0t = z4; B0t = z4; }
    if (ty + 4 == IMG_H) { A5t = z4; B5t = z4; }
    SOBEL_T(A0t, B0t, A1t, B1t, A2t, B2t, A3t, B3t, A4t, B4t, A5t, B5t)

    // ---- Block reduction ----
#pragma unroll
    for (int off = 32; off > 0; off >>= 1)
        lsum += __shfl_down(lsum, off, 64);
    if (lane == 0) wred[w] = lsum;
    __syncthreads();
    if (tid == 0)
        bsums[blockIdx.x] = wred[0] + wred[1] + wred[2] + wred[3];
}

__global__ __launch_bounds__(256) void reduce_final(
    const float* __restrict__ bsums, float* __restrict__ out)
{
    __shared__ float wred[4];
    const int tid = threadIdx.x;
    float s = 0.f;
    for (int i = tid; i < NBLOCKS; i += 256) s += bsums[i];
#pragma unroll
    for (int off = 32; off > 0; off >>= 1)
        s += __shfl_down(s, off, 64);
    if ((tid & 63) == 0) wred[tid >> 6] = s;
    __syncthreads();
    if (tid == 0)
        out[0] = (wred[0] + wred[1] + wred[2] + wred[3]) * (1.0f / (float)NPIX);
}

extern "C" void kernel_launch(void* const* d_in, const int* in_sizes, int n_in,
                              void* d_out, int out_size, void* d_ws, size_t ws_size,
                              hipStream_t stream) {
    const float* yp = (const float*)d_in[0];
    const float* yt = (const float*)d_in[1];
    float* out = (float*)d_out;

    float* bsums = (float*)d_ws;   // 8 KB of workspace
    sobel_loss_kernel<<<NBLOCKS, 256, 0, stream>>>(yp, yt, bsums);
    reduce_final<<<1, 256, 0, stream>>>(bsums, out);
}

// Round 4
// 144.908 us; speedup vs baseline: 1.0233x; 1.0233x over previous
//
#include <hip/hip_runtime.h>

#define IMG_W 512
#define IMG_H 512
#define BATCH 64
#define STRIP_ROWS 16
#define STRIPS_PER_IMG (IMG_H / STRIP_ROWS)        // 32
#define NSTRIPS (BATCH * STRIPS_PER_IMG)           // 2048 strips, 1 per wave
#define NB_MAIN (NSTRIPS / 4)                      // 512 blocks x 4 waves
#define NPIX (BATCH * IMG_W * IMG_H)

typedef float f32x4 __attribute__((ext_vector_type(4)));

__device__ __forceinline__ float fast_sqrtf(float x) {
    return __builtin_amdgcn_sqrtf(x);
}

// R12: continuous-stream redesign. R9/R10/R11 (burst-load phase structures)
// all pin at 44-46us = 672 KB/CU / 6.2 B/cyc: the per-CU vector-memory path
// (ceiling ~10.2 B/cyc, m13) is only ~60% duty-cycled because loads come in
// bursts followed by load-free compute, and co-resident blocks are in phase.
// Fix: per-ROW rolling pipeline, wave-private 16-row strip, no LDS, no
// barriers; constant s_waitcnt vmcnt(6) per row (never 0 until epilogue);
// prefetch row r+3 during row r's compute. Loads in flight ~100% of time.
// Traffic: 36 rows x 2KB x 2048 waves = 147MB -> 576 KB/CU.

#define GLOAD(dst, ptr)                                                        \
    asm volatile("global_load_dwordx4 %0, %1, off" : "=v"(dst) : "v"(ptr))

// rolling-buffer slots (k is a compile-time row index, -1..16)
#define S6(k) (((k) + 1) % 6)
#define S3(k) (((k) + 1) % 3)

// window element j (0..9) of row k: 0 = left halo, 9 = right halo
#define WEL(A, B, HL, HR, k, j)                                                \
    ((j) == 0 ? HL[S3(k)]                                                      \
              : ((j) == 9 ? HR[S3(k)]                                          \
                          : ((j) <= 4 ? A[S6(k)][(j) - 1] : B[S6(k)][(j) - 5])))

// issue the 2 dwordx4 loads of row k (y-clamped; halo rows zeroed post-wait)
#define ISSUE(k, A, B, IMG)                                                    \
    {                                                                          \
        int gy_ = stripy + (k);                                                \
        gy_ = gy_ < 0 ? 0 : (gy_ > IMG_H - 1 ? IMG_H - 1 : gy_);               \
        const float* r_ = (IMG) + ((size_t)gy_ << 9) + x0;                     \
        GLOAD(A[S6(k)], r_);                                                   \
        GLOAD(B[S6(k)], r_ + 4);                                               \
    }

// after row k's data is present: build halo floats + horizontal 1-2-1 sums
#define PREP(k, A, B, HL, HR, HS)                                              \
    {                                                                          \
        float l_ = __shfl_up(B[S6(k)][3], 1, 64);                              \
        float r_ = __shfl_down(A[S6(k)][0], 1, 64);                            \
        HL[S3(k)] = (lane == 0) ? 0.f : l_;                                    \
        HR[S3(k)] = (lane == 63) ? 0.f : r_;                                   \
        _Pragma("unroll")                                                      \
        for (int j = 0; j < 8; ++j)                                            \
            HS[S3(k)][j] = fmaf(2.f, WEL(A, B, HL, HR, k, j + 1),              \
                                WEL(A, B, HL, HR, k, j)) +                     \
                           WEL(A, B, HL, HR, k, j + 2);                        \
    }

// output row r of image p: store magnitudes into magrow
#define OUT_P(r)                                                               \
    {                                                                          \
        float c9_[10];                                                         \
        _Pragma("unroll")                                                      \
        for (int j = 0; j < 10; ++j)                                           \
            c9_[j] = fmaf(2.f, WEL(pA, pB, hlP, hrP, (r), j),                  \
                          WEL(pA, pB, hlP, hrP, (r)-1, j)) +                   \
                     WEL(pA, pB, hlP, hrP, (r) + 1, j);                        \
        _Pragma("unroll")                                                      \
        for (int j = 0; j < 8; ++j) {                                          \
            float gh = hsP[S3((r) + 1)][j] - hsP[S3((r)-1)][j];                \
            float gv = c9_[j + 2] - c9_[j];                                    \
            magrow[j] = fast_sqrtf(fmaf(gv, gv, fmaf(gh, gh, 1e-18f)));        \
        }                                                                      \
    }

// output row r of image t: fused |magt - magp| accumulation
#define OUT_T(r)                                                               \
    {                                                                          \
        float c9_[10];                                                         \
        _Pragma("unroll")                                                      \
        for (int j = 0; j < 10; ++j)                                           \
            c9_[j] = fmaf(2.f, WEL(tA, tB, hlT, hrT, (r), j),                  \
                          WEL(tA, tB, hlT, hrT, (r)-1, j)) +                   \
                     WEL(tA, tB, hlT, hrT, (r) + 1, j);                        \
        _Pragma("unroll")                                                      \
        for (int j = 0; j < 8; ++j) {                                          \
            float gh = hsT[S3((r) + 1)][j] - hsT[S3((r)-1)][j];                \
            float gv = c9_[j + 2] - c9_[j];                                    \
            float mt = fast_sqrtf(fmaf(gv, gv, fmaf(gh, gh, 1e-18f)));         \
            lsum += fabsf(mt - magrow[j]); /* == sqrt(d^2+eps)*(d^2!=0) */     \
        }                                                                      \
    }

// One output row. Issue order (row pairs): ...P_{r+2} T_{r+2} P_{r+3} T_{r+3}
// wait-p at r: outstanding after P_{r+1} = T_{r+1},P_{r+2},T_{r+2} = 6 insts.
// wait-t at r: outstanding after T_{r+1} = P_{r+2},T_{r+2},P_{r+3} = 6 insts.
// Tail: r=14 -> (6,4); r=15 -> (2,0). sched_barrier after each wait: rule #18
// (hipcc hoists reg-only consumers past inline-asm waitcnt otherwise).
#define ITER(r, WP, WT)                                                        \
    {                                                                          \
        float magrow[8];                                                       \
        asm volatile("s_waitcnt vmcnt(" #WP ")" ::: "memory");                 \
        __builtin_amdgcn_sched_barrier(0);                                     \
        if ((r) == 0 && stop_) { pA[S6(-1)] = z4; pB[S6(-1)] = z4; }           \
        if ((r) == 15 && sbot_) { pA[S6(16)] = z4; pB[S6(16)] = z4; }          \
        if ((r) == 0) {                                                        \
            PREP(-1, pA, pB, hlP, hrP, hsP)                                    \
            PREP(0, pA, pB, hlP, hrP, hsP)                                     \
        }                                                                      \
        PREP((r) + 1, pA, pB, hlP, hrP, hsP)                                   \
        if ((r) <= 13) ISSUE((r) + 3, pA, pB, imgp)                            \
        OUT_P(r)                                                               \
        asm volatile("s_waitcnt vmcnt(" #WT ")" ::: "memory");                 \
        __builtin_amdgcn_sched_barrier(0);                                     \
        if ((r) == 0 && stop_) { tA[S6(-1)] = z4; tB[S6(-1)] = z4; }           \
        if ((r) == 15 && sbot_) { tA[S6(16)] = z4; tB[S6(16)] = z4; }          \
        if ((r) == 0) {                                                        \
            PREP(-1, tA, tB, hlT, hrT, hsT)                                    \
            PREP(0, tA, tB, hlT, hrT, hsT)                                     \
        }                                                                      \
        PREP((r) + 1, tA, tB, hlT, hrT, hsT)                                   \
        if ((r) <= 13) ISSUE((r) + 3, tA, tB, imgt)                            \
        OUT_T(r)                                                               \
    }

__global__ __launch_bounds__(256, 2) void sobel_loss_kernel(
    const float* __restrict__ yp, const float* __restrict__ yt,
    float* __restrict__ bsums)
{
    __shared__ float wred[4];

    const int tid  = threadIdx.x;
    const int lane = tid & 63;
    const int w    = tid >> 6;                  // wave id 0..3

    const int bid   = blockIdx.x;
    const int b     = bid >> 3;                 // image (8 blocks/image)
    const int strip = ((bid & 7) << 2) + w;     // strip 0..31 (16 rows each)
    const int stripy = strip << 4;              // first output row
    const int x0    = lane << 3;                // cols x0..x0+7

    const bool stop_ = (strip == 0);
    const bool sbot_ = (strip == STRIPS_PER_IMG - 1);

    const float* imgp = yp + ((size_t)b << 18);
    const float* imgt = yt + ((size_t)b << 18);

    // rolling register state: row k -> slot S6(k); halo/HS -> slot S3(k)
    f32x4 pA[6], pB[6], tA[6], tB[6];
    float hlP[3], hrP[3], hlT[3], hrT[3];
    float hsP[3][8], hsT[3][8];

    const f32x4 z4 = {0.f, 0.f, 0.f, 0.f};
    float lsum = 0.f;

    // ---- prologue: rows -1..2, both images, interleaved p,t ----
    ISSUE(-1, pA, pB, imgp) ISSUE(-1, tA, tB, imgt)
    ISSUE(0,  pA, pB, imgp) ISSUE(0,  tA, tB, imgt)
    ISSUE(1,  pA, pB, imgp) ISSUE(1,  tA, tB, imgt)
    ISSUE(2,  pA, pB, imgp) ISSUE(2,  tA, tB, imgt)

    // ---- 16 output rows, constant counted waits (vmcnt 6/6), tail 6/4, 2/0
    ITER(0, 6, 6)  ITER(1, 6, 6)  ITER(2, 6, 6)  ITER(3, 6, 6)
    ITER(4, 6, 6)  ITER(5, 6, 6)  ITER(6, 6, 6)  ITER(7, 6, 6)
    ITER(8, 6, 6)  ITER(9, 6, 6)  ITER(10, 6, 6) ITER(11, 6, 6)
    ITER(12, 6, 6) ITER(13, 6, 6) ITER(14, 6, 4) ITER(15, 2, 0)

    // ---- Block reduction ----
#pragma unroll
    for (int off = 32; off > 0; off >>= 1)
        lsum += __shfl_down(lsum, off, 64);
    if (lane == 0) wred[w] = lsum;
    __syncthreads();
    if (tid == 0)
        bsums[bid] = wred[0] + wred[1] + wred[2] + wred[3];
}

__global__ __launch_bounds__(256) void reduce_final(
    const float* __restrict__ bsums, float* __restrict__ out)
{
    __shared__ float wred[4];
    const int tid = threadIdx.x;
    float s = 0.f;
    for (int i = tid; i < NB_MAIN; i += 256) s += bsums[i];
#pragma unroll
    for (int off = 32; off > 0; off >>= 1)
        s += __shfl_down(s, off, 64);
    if ((tid & 63) == 0) wred[tid >> 6] = s;
    __syncthreads();
    if (tid == 0)
        out[0] = (wred[0] + wred[1] + wred[2] + wred[3]) * (1.0f / (float)NPIX);
}

extern "C" void kernel_launch(void* const* d_in, const int* in_sizes, int n_in,
                              void* d_out, int out_size, void* d_ws, size_t ws_size,
                              hipStream_t stream) {
    const float* yp = (const float*)d_in[0];
    const float* yt = (const float*)d_in[1];
    float* out = (float*)d_out;

    float* bsums = (float*)d_ws;   // 2 KB of workspace
    sobel_loss_kernel<<<NB_MAIN, 256, 0, stream>>>(yp, yt, bsums);
    reduce_final<<<1, 256, 0, stream>>>(bsums, out);
}